// Round 30
// baseline (117.724 us; speedup 1.0000x reference)
//
#include <hip/hip_runtime.h>
#include <math.h>

#define EMB 1024
#define NHEADS 16
#define HDIM 64
#define BATCH 2
#define SEQ 2048
#define MROWS (BATCH*SEQ)   /* 4096 */
#define LN_EPS 1e-5f
#define GK 1024
#define GN 1024

typedef __attribute__((ext_vector_type(8))) short bf16x8;
typedef __attribute__((ext_vector_type(4))) short s16x4;
typedef __attribute__((ext_vector_type(4))) float f32x4;
typedef __attribute__((ext_vector_type(16))) float f32x16;
typedef __attribute__((ext_vector_type(4))) int int4v;

__device__ __forceinline__ short f2bf(float f) {     // RNE float->bf16
    union { float f; unsigned u; } v; v.f = f;
    unsigned r = v.u + 0x7FFFu + ((v.u >> 16) & 1u);
    return (short)(r >> 16);
}
__device__ __forceinline__ float bf2f(short s) {
    union { unsigned u; float f; } v; v.u = ((unsigned)(unsigned short)s) << 16;
    return v.f;
}
__device__ __forceinline__ unsigned pk2(short a, short b) {
    return (unsigned)(unsigned short)a | ((unsigned)(unsigned short)b << 16);
}
// raw v_exp_f32: 2^x in one instruction (exp2f libm call costs +13us — R17)
__device__ __forceinline__ float fexp2(float x) {
    return __builtin_amdgcn_exp2f(x);
}

__device__ __forceinline__ void gload16(const short* g, short* l) {
    __builtin_amdgcn_global_load_lds(
        (const __attribute__((address_space(1))) unsigned*)g,
        (__attribute__((address_space(3))) unsigned*)l, 16, 0, 0);
}

#define MFMA32(a, b, c) __builtin_amdgcn_mfma_f32_32x32x16_bf16(a, b, c, 0, 0, 0)

// Bank-conflict-free GEMM LDS (verified R20: conflicts 6.29M -> 0):
// physical 16B granule c of row r holds logical granule (c-(r>>1))&3.
#define SRC_G(r, c)  ((((c) - ((r) >> 1)) & 3) * 8)
#define RD_G(r, l4)  ((((l4) + ((r) >> 1)) & 3) * 8)

// ---------------------------------------------------------------------------
// Fused converter: blockIdx.y==0 -> x fp32 -> bf16 hi; y in 1..4 -> weight
// z-1 -> bf16 hi only.
// ---------------------------------------------------------------------------
__global__ __launch_bounds__(256)
void cvt_all(const float* __restrict__ X, short* __restrict__ XH,
             const float* __restrict__ W0, const float* __restrict__ W1,
             const float* __restrict__ W2, const float* __restrict__ W3,
             short* __restrict__ WH)
{
    const int zy = blockIdx.y;
    if (zy == 0) {
        const size_t i = (size_t)blockIdx.x * 1024 + threadIdx.x * 4;
        const float4 v = *(const float4*)&X[i];
        s16x4 h;
        h[0] = f2bf(v.x); h[1] = f2bf(v.y);
        h[2] = f2bf(v.z); h[3] = f2bf(v.w);
        *(s16x4*)&XH[i] = h;
    } else {
        const int z = zy - 1;
        if (blockIdx.x >= 1024) return;        // weights are 1M floats each
        const float* W = (z == 0) ? W0 : (z == 1) ? W1 : (z == 2) ? W2 : W3;
        const size_t i = (size_t)blockIdx.x * 1024 + threadIdx.x * 4;
        const float4 v = *(const float4*)&W[i];
        s16x4 h;
        h[0] = f2bf(v.x); h[1] = f2bf(v.y);
        h[2] = f2bf(v.z); h[3] = f2bf(v.w);
        *(s16x4*)&WH[((size_t)z << 20) + i] = h;
    }
}

// ---------------------------------------------------------------------------
// Fused K/Q/V MFMA GEMM, pure bf16, 3-buffer counted-vmcnt pipeline (R27).
// z=0: K hi + LN. z=1: Q hi + LN. z=2: V^T hi.
// ---------------------------------------------------------------------------
__global__ __launch_bounds__(256, 3)
void gemm_kqv(const short* __restrict__ Xh, const short* __restrict__ W4h,
              const float* __restrict__ kg, const float* __restrict__ kb,
              const float* __restrict__ qg, const float* __restrict__ qb,
              float scaleK, float scaleQ,
              short* __restrict__ KhP, short* __restrict__ QhP,
              short* __restrict__ VTh)
{
    __shared__ short AhS[3][128][32], BhS[3][128][32];

    const int t   = threadIdx.x;
    const int ln  = t & 63, wv = t >> 6;
    const int l15 = ln & 15, l4 = ln >> 4;
    const int m0  = blockIdx.y * 128;
    const int n0  = blockIdx.x * 128;
    const int z   = blockIdx.z;
    const int wr  = (wv >> 1) * 64, wc = (wv & 1) * 64;

    const short* Bh = W4h + ((size_t)z << 20);

    const short* gplane = (wv < 2) ? Xh : Bh;
    const int    grow0  = (wv < 2) ? m0 : n0;
    short* lbase = (wv < 2) ? &AhS[0][0][0] : &BhS[0][0][0];
    const int s0 = (wv & 1) ? 4 : 0;           // 4 segs per wave, balanced

    f32x4 acc[4][4];
    #pragma unroll
    for (int i = 0; i < 4; ++i)
        #pragma unroll
        for (int j = 0; j < 4; ++j) acc[i][j] = (f32x4){0.f, 0.f, 0.f, 0.f};

    // prologue: stage k-steps 0 and 1 into bufs 0,1 (8 loads in flight)
    #pragma unroll
    for (int s = 0; s < 4; ++s) {
        const int chunk = (s0 + s) * 64 + ln;
        const int r = chunk >> 2, c = chunk & 3;
        gload16(gplane + (size_t)(grow0 + r) * GK + SRC_G(r, c),
                lbase + (s0 + s) * 512);
    }
    #pragma unroll
    for (int s = 0; s < 4; ++s) {
        const int chunk = (s0 + s) * 64 + ln;
        const int r = chunk >> 2, c = chunk & 3;
        gload16(gplane + (size_t)(grow0 + r) * GK + 32 + SRC_G(r, c),
                lbase + 4096 + (s0 + s) * 512);
    }
    asm volatile("s_waitcnt vmcnt(4)" ::: "memory");   // buf0 landed
    __builtin_amdgcn_s_barrier();

    int cur = 0;
    for (int i = 0; i < 32; ++i) {
        const int cur2 = (cur == 0) ? 2 : cur - 1;     // (i+2)%3
        if (i + 2 < 32) {          // stage k-step i+2 into freed buffer
            short* lp = lbase + cur2 * 4096;
            const int kof = (i + 2) * 32;
            #pragma unroll
            for (int s = 0; s < 4; ++s) {
                const int chunk = (s0 + s) * 64 + ln;
                const int r = chunk >> 2, c = chunk & 3;
                gload16(gplane + (size_t)(grow0 + r) * GK + kof + SRC_G(r, c),
                        lp + (s0 + s) * 512);
            }
        }

        bf16x8 ah[4], bh[4];
        #pragma unroll
        for (int f = 0; f < 4; ++f) {
            const int ra = wr + f * 16 + l15;
            const int rb = wc + f * 16 + l15;
            ah[f] = *(const bf16x8*)&AhS[cur][ra][RD_G(ra, l4)];
            bh[f] = *(const bf16x8*)&BhS[cur][rb][RD_G(rb, l4)];
        }
        #pragma unroll
        for (int i2 = 0; i2 < 4; ++i2)
            #pragma unroll
            for (int j = 0; j < 4; ++j)
                acc[i2][j] = __builtin_amdgcn_mfma_f32_16x16x32_bf16(ah[i2], bh[j], acc[i2][j], 0, 0, 0);

        if (i + 2 < 32) {
            asm volatile("s_waitcnt vmcnt(4)" ::: "memory");  // buf i+1 landed
        } else if (i + 1 < 32) {
            asm volatile("s_waitcnt vmcnt(0)" ::: "memory");  // tail: drain
        }
        __builtin_amdgcn_s_barrier();
        cur = (cur == 2) ? 0 : cur + 1;
    }

    if (z < 2) {
        const float* gamma = (z == 0) ? kg : qg;
        const float* beta  = (z == 0) ? kb : qb;
        short* OutH = (z == 0) ? KhP : QhP;
        const float scl = (z == 0) ? scaleK : scaleQ;
        const int n_head = (n0 + wc) >> 6;
        float g4[4], b4[4];
        #pragma unroll
        for (int f = 0; f < 4; ++f) {
            g4[f] = gamma[f * 16 + l15];
            b4[f] = beta [f * 16 + l15];
        }
        #pragma unroll
        for (int i = 0; i < 4; ++i)
            #pragma unroll
            for (int j = 0; j < 4; ++j) {
                const float v0 = acc[i][0][j], v1 = acc[i][1][j];
                const float v2 = acc[i][2][j], v3 = acc[i][3][j];
                float s1 = v0 + v1 + v2 + v3;
                float s2 = v0*v0 + v1*v1 + v2*v2 + v3*v3;
                s1 += __shfl_xor(s1, 1); s2 += __shfl_xor(s2, 1);
                s1 += __shfl_xor(s1, 2); s2 += __shfl_xor(s2, 2);
                s1 += __shfl_xor(s1, 4); s2 += __shfl_xor(s2, 4);
                s1 += __shfl_xor(s1, 8); s2 += __shfl_xor(s2, 8);
                const float mu  = s1 * (1.f / 64.f);
                const float var = s2 * (1.f / 64.f) - mu * mu;
                const float rs  = rsqrtf(var + LN_EPS);
                const int m = m0 + wr + i * 16 + l4 * 4 + j;   // m = b*SEQ + t
                const size_t orow =
                    ((size_t)((m >> 11) * NHEADS + n_head) * SEQ + (m & (SEQ - 1))) * HDIM;
                #pragma unroll
                for (int f = 0; f < 4; ++f) {
                    const float y = ((acc[i][f][j] - mu) * rs * g4[f] + b4[f]) * scl;
                    OutH[orow + f * 16 + l15] = f2bf(y);
                }
            }
    } else {
        // V^T epilogue: hi plane only (attn reads V as plain bf16)
        #pragma unroll
        for (int i = 0; i < 4; ++i)
            #pragma unroll
            for (int f = 0; f < 4; ++f) {
                s16x4 h4;
                #pragma unroll
                for (int j = 0; j < 4; ++j) h4[j] = f2bf(acc[i][f][j]);
                const int n  = n0 + wc + f * 16 + l15;
                const int hh = n >> 6, dd = n & 63;
                const int mb = m0 + wr + i * 16 + l4 * 4;      // j=0 row
                const size_t oa =
                    (((size_t)((mb >> 11) * NHEADS + hh)) * HDIM + dd) * SEQ + (mb & (SEQ - 1));
                *(s16x4*)&VTh[oa] = h4;
            }
    }
}

// ---------------------------------------------------------------------------
// Final GEMM, pure bf16, 2-phase dbuf (R26 measured config, unchanged).
// ---------------------------------------------------------------------------
__global__ __launch_bounds__(256, 2)
void gemm_out(const short* __restrict__ Ah, const short* __restrict__ Bh,
              const float* __restrict__ bias, float* __restrict__ OutF)
{
    __shared__ short AhS[2][64][32], BhS[2][128][32];

    const int t   = threadIdx.x;
    const int ln  = t & 63, wv = t >> 6;
    const int l15 = ln & 15, l4 = ln >> 4;
    const int m0  = blockIdx.y * 64;
    const int n0  = blockIdx.x * 128;
    const int wr  = (wv >> 1) * 32, wc = (wv & 1) * 64;

    const short* gplane = (wv == 0) ? Ah : Bh;
    const int    grow0  = (wv == 0) ? m0 : n0;
    const int    s0     = (wv == 2) ? 4 : 0;
    const int    nseg   = (wv < 3) ? 4 : 0;
    const int    bstep  = (wv == 0) ? 2048 : 4096;      // shorts per buffer
    short* lbase = (wv == 0) ? &AhS[0][0][0] : &BhS[0][0][0];

    f32x4 acc[2][4];
    #pragma unroll
    for (int i = 0; i < 2; ++i)
        #pragma unroll
        for (int j = 0; j < 4; ++j) acc[i][j] = (f32x4){0.f, 0.f, 0.f, 0.f};

    for (int s = 0; s < nseg; ++s) {
        const int chunk = (s0 + s) * 64 + ln;
        const int r = chunk >> 2, c = chunk & 3;
        gload16(gplane + (size_t)(grow0 + r) * GK + SRC_G(r, c),
                lbase + (s0 + s) * 512);
    }
    __syncthreads();

    int cur = 0;
    for (int k0 = 0; k0 < GK; k0 += 32) {
        if (k0 + 32 < GK) {
            short* lp = lbase + (cur ^ 1) * bstep;
            for (int s = 0; s < nseg; ++s) {
                const int chunk = (s0 + s) * 64 + ln;
                const int r = chunk >> 2, c = chunk & 3;
                gload16(gplane + (size_t)(grow0 + r) * GK + k0 + 32 + SRC_G(r, c),
                        lp + (s0 + s) * 512);
            }
        }

        bf16x8 ah[2], bh[4];
        #pragma unroll
        for (int f = 0; f < 2; ++f) {
            const int ra = wr + f * 16 + l15;
            ah[f] = *(const bf16x8*)&AhS[cur][ra][RD_G(ra, l4)];
        }
        #pragma unroll
        for (int f = 0; f < 4; ++f) {
            const int rb = wc + f * 16 + l15;
            bh[f] = *(const bf16x8*)&BhS[cur][rb][RD_G(rb, l4)];
        }
        #pragma unroll
        for (int i = 0; i < 2; ++i)
            #pragma unroll
            for (int j = 0; j < 4; ++j)
                acc[i][j] = __builtin_amdgcn_mfma_f32_16x16x32_bf16(ah[i], bh[j], acc[i][j], 0, 0, 0);

        __syncthreads();
        cur ^= 1;
    }

    float b4[4];
    #pragma unroll
    for (int f = 0; f < 4; ++f) b4[f] = bias[n0 + wc + f * 16 + l15];
    #pragma unroll
    for (int i = 0; i < 2; ++i)
        #pragma unroll
        for (int j = 0; j < 4; ++j) {
            const int m = m0 + wr + i * 16 + l4 * 4 + j;
            const size_t row = (size_t)m * GN + n0 + wc;
            #pragma unroll
            for (int f = 0; f < 4; ++f)
                OutF[row + f * 16 + l15] = acc[i][f][j] + b4[f];
        }
}

// ---------------------------------------------------------------------------
// Causal flash attention, 1-term bf16, KVBLK=128 rounds + exact defer-rescale
// (R29) + T1 XCD-AWARE SWIZZLE: linear block id lin -> xcd=lin&7, m=lin>>3,
// bh=xcd*4+(m>>4), qt direction flips on bit 5 (CU pair-balance preserved:
// co-resident m, m+32 get opposite directions). All 16 q-blocks of a head
// land on ONE XCD -> per-XCD L2 working set 4 heads x (Q+K+V) = 3MB < 4MB
// -> K/V re-reads become L2 hits (R29 FETCH was 55MB vs 24MB unique).
// ---------------------------------------------------------------------------
__global__ __launch_bounds__(256, 2)
void attn_mfma(const short* __restrict__ Qh, const short* __restrict__ Kh,
               const short* __restrict__ Vh, short* __restrict__ Oh)
{
    __shared__ short KhS[2][64][64];
    __shared__ short VhS[2][64][64];

    const int t    = threadIdx.x;
    const int lane = t & 63, wv = t >> 6;            // 4 waves
    const int l31  = lane & 31, hb = lane >> 5;

    // XCD-aware (bh, qt) derivation — bijective over 512 blocks
    const int lin = (int)blockIdx.y * 16 + (int)blockIdx.x;
    const int xcd = lin & 7;
    const int m   = lin >> 3;
    const int bh  = xcd * 4 + (m >> 4);
    const int qtr = m & 15;
    const int qt  = ((m >> 5) & 1) ? qtr : 15 - qtr;

    const int bb   = bh >> 4, hh = bh & 15;
    const int q0   = qt * 128;
    const int wq0  = wv * 32;

    const size_t kpan = (size_t)bh * SEQ * HDIM;   // [t][d] panels (Q,K)
    const size_t vpan = (size_t)bh * HDIM * SEQ;   // [d][t] panels (V^T)

    const int sr0  = t >> 3, sr1 = 32 + (t >> 3);
    const int scg  = t & 7;
    const int soff = scg * 8;
    const int lc0  = (scg ^ (sr0 & 7)) * 8;        // (sr1&7)==(sr0&7)

    // Q B-frags: col q = q0+wq0+l31, k-dim d = ds*16 + hb*8 + j
    bf16x8 qfh[4];
    {
        const size_t qrow = kpan + (size_t)(q0 + wq0 + l31) * HDIM;
        #pragma unroll
        for (int ds = 0; ds < 4; ++ds)
            qfh[ds] = *(const bf16x8*)&Qh[qrow + ds * 16 + hb * 8];
    }

    f32x16 oacc0 = (f32x16)(0.0f), oacc1 = (f32x16)(0.0f);
    float m_run = -1e30f, l_run = 0.f;

    const int NR = qt + 1;                 // rounds of 128 k

    int4v pK[2][2], pV[2][2];              // [k-half][row-half]
    #pragma unroll
    for (int h = 0; h < 2; ++h) {
        const int kb0 = h * 64;
        pK[h][0] = *(const int4v*)&Kh[kpan + (size_t)(kb0 + sr0) * HDIM + soff];
        pK[h][1] = *(const int4v*)&Kh[kpan + (size_t)(kb0 + sr1) * HDIM + soff];
        pV[h][0] = *(const int4v*)&Vh[vpan + (size_t)sr0 * SEQ + kb0 + soff];
        pV[h][1] = *(const int4v*)&Vh[vpan + (size_t)sr1 * SEQ + kb0 + soff];
    }

    for (int rr = 0; rr < NR; ++rr) {
        const int k0 = rr * 128;

        __syncthreads();           // all waves done reading prev K/V

        #pragma unroll
        for (int h = 0; h < 2; ++h) {
            *(int4v*)&KhS[h][sr0][lc0] = pK[h][0];
            *(int4v*)&KhS[h][sr1][lc0] = pK[h][1];
            *(int4v*)&VhS[h][sr0][lc0] = pV[h][0];
            *(int4v*)&VhS[h][sr1][lc0] = pV[h][1];
        }

        if (rr + 1 < NR) {         // T14: issue next round's loads under compute
            const int kn = k0 + 128;
            #pragma unroll
            for (int h = 0; h < 2; ++h) {
                const int kb0 = kn + h * 64;
                pK[h][0] = *(const int4v*)&Kh[kpan + (size_t)(kb0 + sr0) * HDIM + soff];
                pK[h][1] = *(const int4v*)&Kh[kpan + (size_t)(kb0 + sr1) * HDIM + soff];
                pV[h][0] = *(const int4v*)&Vh[vpan + (size_t)sr0 * SEQ + kb0 + soff];
                pV[h][1] = *(const int4v*)&Vh[vpan + (size_t)sr1 * SEQ + kb0 + soff];
            }
        }
        __syncthreads();           // current round's LDS ready

        #pragma unroll
        for (int half = 0; half < 2; ++half) {
            const int kk0 = k0 + half * 64;
            if (kk0 > q0 + wq0 + 31) continue;   // sub-tile future for wave

            // ---- QK^T 1-term: s0 (k rows 0-31), s1 (k rows 32-63) ----
            f32x16 s0 = (f32x16)(0.0f), s1 = (f32x16)(0.0f);
            #pragma unroll
            for (int ds = 0; ds < 4; ++ds) {
                const int g = ((ds * 2 + hb) ^ (l31 & 7)) * 8;
                const bf16x8 kh0 = *(const bf16x8*)&KhS[half][l31][g];
                const bf16x8 kh1 = *(const bf16x8*)&KhS[half][32 + l31][g];
                s0 = MFMA32(kh0, qfh[ds], s0);
                s1 = MFMA32(kh1, qfh[ds], s1);
            }

            // ---- causal mask (diag kept) ----
            if (kk0 + 63 > q0 + wq0) {
                const int qg = q0 + wq0 + l31;
                #pragma unroll
                for (int reg = 0; reg < 16; ++reg) {
                    const int kk = kk0 + (reg & 3) + 8 * (reg >> 2) + 4 * hb;
                    if (kk > qg)      s0[reg] = -1e30f;
                    if (kk + 32 > qg) s1[reg] = -1e30f;
                }
            }

            // ---- online softmax; exact skip of rescale when max static ----
            {
                float mx = -1e30f;
                #pragma unroll
                for (int reg = 0; reg < 16; ++reg)
                    mx = fmaxf(mx, fmaxf(s0[reg], s1[reg]));
                mx = fmaxf(mx, __shfl_xor(mx, 32));
                if (__any(mx > m_run)) {
                    const float mnew = fmaxf(m_run, mx);
                    const float scf  = fexp2(m_run - mnew);
                    m_run = mnew;
                    l_run *= scf;
                    #pragma unroll
                    for (int reg = 0; reg < 16; ++reg) {
                        oacc0[reg] *= scf;
                        oacc1[reg] *= scf;
                    }
                }
                float ls = 0.f;
                #pragma unroll
                for (int reg = 0; reg < 16; ++reg) {
                    const float p0 = fexp2(s0[reg] - m_run);
                    const float p1 = fexp2(s1[reg] - m_run);
                    s0[reg] = p0; s1[reg] = p1;
                    ls += p0 + p1;
                }
                ls += __shfl_xor(ls, 32);
                l_run += ls;
            }

            // ---- PV: per 16-k step, hi-only P B-frag in-register ----
            #pragma unroll
            for (int ks = 0; ks < 4; ++ks) {
                short h8[8];
                #pragma unroll
                for (int a = 0; a < 8; ++a) {
                    const float p = (ks >= 2) ? s1[(ks & 1) * 8 + a]
                                              : s0[(ks & 1) * 8 + a];
                    h8[a] = f2bf(p);
                }
                const unsigned hA0 = pk2(h8[0], h8[1]), hA1 = pk2(h8[2], h8[3]);
                const unsigned hB0 = pk2(h8[4], h8[5]), hB1 = pk2(h8[6], h8[7]);
                const unsigned hr0 = (unsigned)__shfl_xor((int)(hb ? hA0 : hB0), 32);
                const unsigned hr1 = (unsigned)__shfl_xor((int)(hb ? hA1 : hB1), 32);
                const int4v wih = (int4v){(int)(hb ? hr0 : hA0), (int)(hb ? hr1 : hA1),
                                          (int)(hb ? hB0 : hr0), (int)(hb ? hB1 : hr1)};
                const bf16x8 pfh = __builtin_bit_cast(bf16x8, wih);

                const int gv = ((ks * 2 + hb) ^ (l31 & 7)) * 8;
                const bf16x8 vh0 = *(const bf16x8*)&VhS[half][l31][gv];
                const bf16x8 vh1 = *(const bf16x8*)&VhS[half][32 + l31][gv];
                oacc0 = MFMA32(vh0, pfh, oacc0);
                oacc1 = MFMA32(vh1, pfh, oacc1);
            }
        }
    }

    // epilogue: normalize, write O hi-only (downstream GEMM is pure bf16)
    const float inv = 1.f / l_run;
    const int q = q0 + wq0 + l31;
    const size_t row = ((size_t)(bb * SEQ + q)) * EMB + hh * HDIM;
    #pragma unroll
    for (int db = 0; db < 2; ++db)
        #pragma unroll
        for (int b = 0; b < 4; ++b) {
            s16x4 h4;
            #pragma unroll
            for (int a = 0; a < 4; ++a)
                h4[a] = f2bf((db ? oacc1[4 * b + a] : oacc0[4 * b + a]) * inv);
            const int d0 = db * 32 + 8 * b + 4 * hb;
            *(s16x4*)&Oh[row + d0] = h4;
        }
}

// ---------------------------------------------------------------------------
extern "C" void kernel_launch(void* const* d_in, const int* in_sizes, int n_in,
                              void* d_out, int out_size, void* d_ws, size_t ws_size,
                              hipStream_t stream)
{
    const float* x  = (const float*)d_in[0];
    const float* Wk = (const float*)d_in[1];
    const float* Wq = (const float*)d_in[2];
    const float* Wv = (const float*)d_in[3];
    const float* Wu = (const float*)d_in[4];
    const float* bu = (const float*)d_in[5];
    const float* kg = (const float*)d_in[6];
    const float* kb = (const float*)d_in[7];
    const float* qg = (const float*)d_in[8];
    const float* qb = (const float*)d_in[9];
    float* out = (float*)d_out;

    // ws map (32 MB):
    //  [ 0, 8M) Xh -> reused as Oh (attn out)
    //  [ 8,16M) Kh
    //  [16,24M) Qh
    //  [24,32M) W4h (4x2MB)
    // d_out: [0,8M) VTh (dead before final GEMM writes) -> final fp32 out
    char* w = (char*)d_ws;
    short* XhP = (short*)(w);
    short* KhP = (short*)(w + (8u  << 20));
    short* QhP = (short*)(w + (16u << 20));
    short* W4h = (short*)(w + (24u << 20));
    short* VTh = (short*)d_out;

    const float inv4 = 0.17677669529663687f;   // 1024^(-1/4)
    const float l2e  = 1.4426950408889634f;

    cvt_all<<<dim3(4096, 5), 256, 0, stream>>>(x, XhP, Wk, Wq, Wv, Wu, W4h);

    gemm_kqv<<<dim3(GN / 128, MROWS / 128, 3), 256, 0, stream>>>(
        XhP, W4h, kg, kb, qg, qb, inv4, inv4 * l2e,
        KhP, QhP, VTh);

    attn_mfma<<<dim3(SEQ / 128, BATCH * NHEADS), 256, 0, stream>>>(
        QhP, KhP, VTh, XhP);

    gemm_out<<<dim3(GN / 128, MROWS / 64), 256, 0, stream>>>(
        XhP, W4h + (3u << 20), bu, out);
}

// Round 31
// 113.353 us; speedup vs baseline: 1.0386x; 1.0386x over previous
//
#include <hip/hip_runtime.h>
#include <math.h>

#define EMB 1024
#define NHEADS 16
#define HDIM 64
#define BATCH 2
#define SEQ 2048
#define MROWS (BATCH*SEQ)   /* 4096 */
#define LN_EPS 1e-5f
#define GK 1024
#define GN 1024

typedef __attribute__((ext_vector_type(8))) short bf16x8;
typedef __attribute__((ext_vector_type(4))) short s16x4;
typedef __attribute__((ext_vector_type(4))) float f32x4;
typedef __attribute__((ext_vector_type(16))) float f32x16;
typedef __attribute__((ext_vector_type(4))) int int4v;

__device__ __forceinline__ short f2bf(float f) {     // RNE float->bf16
    union { float f; unsigned u; } v; v.f = f;
    unsigned r = v.u + 0x7FFFu + ((v.u >> 16) & 1u);
    return (short)(r >> 16);
}
__device__ __forceinline__ float bf2f(short s) {
    union { unsigned u; float f; } v; v.u = ((unsigned)(unsigned short)s) << 16;
    return v.f;
}
// HW packed f32->bf16 (RNE): dst = {lo: bf16(a), hi: bf16(b)} in 1 VALU inst
__device__ __forceinline__ unsigned cvtpk(float a, float b) {
    unsigned r;
    asm("v_cvt_pk_bf16_f32 %0, %1, %2" : "=v"(r) : "v"(a), "v"(b));
    return r;
}
// raw v_exp_f32: 2^x in one instruction (exp2f libm call costs +13us — R17)
__device__ __forceinline__ float fexp2(float x) {
    return __builtin_amdgcn_exp2f(x);
}

__device__ __forceinline__ void gload16(const short* g, short* l) {
    __builtin_amdgcn_global_load_lds(
        (const __attribute__((address_space(1))) unsigned*)g,
        (__attribute__((address_space(3))) unsigned*)l, 16, 0, 0);
}

#define MFMA32(a, b, c) __builtin_amdgcn_mfma_f32_32x32x16_bf16(a, b, c, 0, 0, 0)

// Bank-conflict-free GEMM LDS (verified R20: conflicts 6.29M -> 0):
// physical 16B granule c of row r holds logical granule (c-(r>>1))&3.
#define SRC_G(r, c)  ((((c) - ((r) >> 1)) & 3) * 8)
#define RD_G(r, l4)  ((((l4) + ((r) >> 1)) & 3) * 8)

// ---------------------------------------------------------------------------
// Fused converter: blockIdx.y==0 -> x fp32 -> bf16 hi; y in 1..4 -> weight
// z-1 -> bf16 hi only.
// ---------------------------------------------------------------------------
__global__ __launch_bounds__(256)
void cvt_all(const float* __restrict__ X, short* __restrict__ XH,
             const float* __restrict__ W0, const float* __restrict__ W1,
             const float* __restrict__ W2, const float* __restrict__ W3,
             short* __restrict__ WH)
{
    const int zy = blockIdx.y;
    if (zy == 0) {
        const size_t i = (size_t)blockIdx.x * 1024 + threadIdx.x * 4;
        const float4 v = *(const float4*)&X[i];
        s16x4 h;
        h[0] = f2bf(v.x); h[1] = f2bf(v.y);
        h[2] = f2bf(v.z); h[3] = f2bf(v.w);
        *(s16x4*)&XH[i] = h;
    } else {
        const int z = zy - 1;
        if (blockIdx.x >= 1024) return;        // weights are 1M floats each
        const float* W = (z == 0) ? W0 : (z == 1) ? W1 : (z == 2) ? W2 : W3;
        const size_t i = (size_t)blockIdx.x * 1024 + threadIdx.x * 4;
        const float4 v = *(const float4*)&W[i];
        s16x4 h;
        h[0] = f2bf(v.x); h[1] = f2bf(v.y);
        h[2] = f2bf(v.z); h[3] = f2bf(v.w);
        *(s16x4*)&WH[((size_t)z << 20) + i] = h;
    }
}

// ---------------------------------------------------------------------------
// Fused K/Q/V MFMA GEMM, pure bf16, 3-buffer counted-vmcnt pipeline (R27).
// z=0: K hi + LN. z=1: Q hi + LN. z=2: V^T hi.
// ---------------------------------------------------------------------------
__global__ __launch_bounds__(256, 3)
void gemm_kqv(const short* __restrict__ Xh, const short* __restrict__ W4h,
              const float* __restrict__ kg, const float* __restrict__ kb,
              const float* __restrict__ qg, const float* __restrict__ qb,
              float scaleK, float scaleQ,
              short* __restrict__ KhP, short* __restrict__ QhP,
              short* __restrict__ VTh)
{
    __shared__ short AhS[3][128][32], BhS[3][128][32];

    const int t   = threadIdx.x;
    const int ln  = t & 63, wv = t >> 6;
    const int l15 = ln & 15, l4 = ln >> 4;
    const int m0  = blockIdx.y * 128;
    const int n0  = blockIdx.x * 128;
    const int z   = blockIdx.z;
    const int wr  = (wv >> 1) * 64, wc = (wv & 1) * 64;

    const short* Bh = W4h + ((size_t)z << 20);

    const short* gplane = (wv < 2) ? Xh : Bh;
    const int    grow0  = (wv < 2) ? m0 : n0;
    short* lbase = (wv < 2) ? &AhS[0][0][0] : &BhS[0][0][0];
    const int s0 = (wv & 1) ? 4 : 0;           // 4 segs per wave, balanced

    f32x4 acc[4][4];
    #pragma unroll
    for (int i = 0; i < 4; ++i)
        #pragma unroll
        for (int j = 0; j < 4; ++j) acc[i][j] = (f32x4){0.f, 0.f, 0.f, 0.f};

    // prologue: stage k-steps 0 and 1 into bufs 0,1 (8 loads in flight)
    #pragma unroll
    for (int s = 0; s < 4; ++s) {
        const int chunk = (s0 + s) * 64 + ln;
        const int r = chunk >> 2, c = chunk & 3;
        gload16(gplane + (size_t)(grow0 + r) * GK + SRC_G(r, c),
                lbase + (s0 + s) * 512);
    }
    #pragma unroll
    for (int s = 0; s < 4; ++s) {
        const int chunk = (s0 + s) * 64 + ln;
        const int r = chunk >> 2, c = chunk & 3;
        gload16(gplane + (size_t)(grow0 + r) * GK + 32 + SRC_G(r, c),
                lbase + 4096 + (s0 + s) * 512);
    }
    asm volatile("s_waitcnt vmcnt(4)" ::: "memory");   // buf0 landed
    __builtin_amdgcn_s_barrier();

    int cur = 0;
    for (int i = 0; i < 32; ++i) {
        const int cur2 = (cur == 0) ? 2 : cur - 1;     // (i+2)%3
        if (i + 2 < 32) {          // stage k-step i+2 into freed buffer
            short* lp = lbase + cur2 * 4096;
            const int kof = (i + 2) * 32;
            #pragma unroll
            for (int s = 0; s < 4; ++s) {
                const int chunk = (s0 + s) * 64 + ln;
                const int r = chunk >> 2, c = chunk & 3;
                gload16(gplane + (size_t)(grow0 + r) * GK + kof + SRC_G(r, c),
                        lp + (s0 + s) * 512);
            }
        }

        bf16x8 ah[4], bh[4];
        #pragma unroll
        for (int f = 0; f < 4; ++f) {
            const int ra = wr + f * 16 + l15;
            const int rb = wc + f * 16 + l15;
            ah[f] = *(const bf16x8*)&AhS[cur][ra][RD_G(ra, l4)];
            bh[f] = *(const bf16x8*)&BhS[cur][rb][RD_G(rb, l4)];
        }
        #pragma unroll
        for (int i2 = 0; i2 < 4; ++i2)
            #pragma unroll
            for (int j = 0; j < 4; ++j)
                acc[i2][j] = __builtin_amdgcn_mfma_f32_16x16x32_bf16(ah[i2], bh[j], acc[i2][j], 0, 0, 0);

        if (i + 2 < 32) {
            asm volatile("s_waitcnt vmcnt(4)" ::: "memory");  // buf i+1 landed
        } else if (i + 1 < 32) {
            asm volatile("s_waitcnt vmcnt(0)" ::: "memory");  // tail: drain
        }
        __builtin_amdgcn_s_barrier();
        cur = (cur == 2) ? 0 : cur + 1;
    }

    if (z < 2) {
        const float* gamma = (z == 0) ? kg : qg;
        const float* beta  = (z == 0) ? kb : qb;
        short* OutH = (z == 0) ? KhP : QhP;
        const float scl = (z == 0) ? scaleK : scaleQ;
        const int n_head = (n0 + wc) >> 6;
        float g4[4], b4[4];
        #pragma unroll
        for (int f = 0; f < 4; ++f) {
            g4[f] = gamma[f * 16 + l15];
            b4[f] = beta [f * 16 + l15];
        }
        #pragma unroll
        for (int i = 0; i < 4; ++i)
            #pragma unroll
            for (int j = 0; j < 4; ++j) {
                const float v0 = acc[i][0][j], v1 = acc[i][1][j];
                const float v2 = acc[i][2][j], v3 = acc[i][3][j];
                float s1 = v0 + v1 + v2 + v3;
                float s2 = v0*v0 + v1*v1 + v2*v2 + v3*v3;
                s1 += __shfl_xor(s1, 1); s2 += __shfl_xor(s2, 1);
                s1 += __shfl_xor(s1, 2); s2 += __shfl_xor(s2, 2);
                s1 += __shfl_xor(s1, 4); s2 += __shfl_xor(s2, 4);
                s1 += __shfl_xor(s1, 8); s2 += __shfl_xor(s2, 8);
                const float mu  = s1 * (1.f / 64.f);
                const float var = s2 * (1.f / 64.f) - mu * mu;
                const float rs  = rsqrtf(var + LN_EPS);
                const int m = m0 + wr + i * 16 + l4 * 4 + j;   // m = b*SEQ + t
                const size_t orow =
                    ((size_t)((m >> 11) * NHEADS + n_head) * SEQ + (m & (SEQ - 1))) * HDIM;
                #pragma unroll
                for (int f = 0; f < 4; ++f) {
                    const float y = ((acc[i][f][j] - mu) * rs * g4[f] + b4[f]) * scl;
                    OutH[orow + f * 16 + l15] = f2bf(y);
                }
            }
    } else {
        // V^T epilogue: hi plane only (attn reads V as plain bf16)
        #pragma unroll
        for (int i = 0; i < 4; ++i)
            #pragma unroll
            for (int f = 0; f < 4; ++f) {
                s16x4 h4;
                #pragma unroll
                for (int j = 0; j < 4; ++j) h4[j] = f2bf(acc[i][f][j]);
                const int n  = n0 + wc + f * 16 + l15;
                const int hh = n >> 6, dd = n & 63;
                const int mb = m0 + wr + i * 16 + l4 * 4;      // j=0 row
                const size_t oa =
                    (((size_t)((mb >> 11) * NHEADS + hh)) * HDIM + dd) * SEQ + (mb & (SEQ - 1));
                *(s16x4*)&VTh[oa] = h4;
            }
    }
}

// ---------------------------------------------------------------------------
// Final GEMM, pure bf16, 2-phase dbuf (R26 measured config, unchanged).
// ---------------------------------------------------------------------------
__global__ __launch_bounds__(256, 2)
void gemm_out(const short* __restrict__ Ah, const short* __restrict__ Bh,
              const float* __restrict__ bias, float* __restrict__ OutF)
{
    __shared__ short AhS[2][64][32], BhS[2][128][32];

    const int t   = threadIdx.x;
    const int ln  = t & 63, wv = t >> 6;
    const int l15 = ln & 15, l4 = ln >> 4;
    const int m0  = blockIdx.y * 64;
    const int n0  = blockIdx.x * 128;
    const int wr  = (wv >> 1) * 32, wc = (wv & 1) * 64;

    const short* gplane = (wv == 0) ? Ah : Bh;
    const int    grow0  = (wv == 0) ? m0 : n0;
    const int    s0     = (wv == 2) ? 4 : 0;
    const int    nseg   = (wv < 3) ? 4 : 0;
    const int    bstep  = (wv == 0) ? 2048 : 4096;      // shorts per buffer
    short* lbase = (wv == 0) ? &AhS[0][0][0] : &BhS[0][0][0];

    f32x4 acc[2][4];
    #pragma unroll
    for (int i = 0; i < 2; ++i)
        #pragma unroll
        for (int j = 0; j < 4; ++j) acc[i][j] = (f32x4){0.f, 0.f, 0.f, 0.f};

    for (int s = 0; s < nseg; ++s) {
        const int chunk = (s0 + s) * 64 + ln;
        const int r = chunk >> 2, c = chunk & 3;
        gload16(gplane + (size_t)(grow0 + r) * GK + SRC_G(r, c),
                lbase + (s0 + s) * 512);
    }
    __syncthreads();

    int cur = 0;
    for (int k0 = 0; k0 < GK; k0 += 32) {
        if (k0 + 32 < GK) {
            short* lp = lbase + (cur ^ 1) * bstep;
            for (int s = 0; s < nseg; ++s) {
                const int chunk = (s0 + s) * 64 + ln;
                const int r = chunk >> 2, c = chunk & 3;
                gload16(gplane + (size_t)(grow0 + r) * GK + k0 + 32 + SRC_G(r, c),
                        lp + (s0 + s) * 512);
            }
        }

        bf16x8 ah[2], bh[4];
        #pragma unroll
        for (int f = 0; f < 2; ++f) {
            const int ra = wr + f * 16 + l15;
            ah[f] = *(const bf16x8*)&AhS[cur][ra][RD_G(ra, l4)];
        }
        #pragma unroll
        for (int f = 0; f < 4; ++f) {
            const int rb = wc + f * 16 + l15;
            bh[f] = *(const bf16x8*)&BhS[cur][rb][RD_G(rb, l4)];
        }
        #pragma unroll
        for (int i = 0; i < 2; ++i)
            #pragma unroll
            for (int j = 0; j < 4; ++j)
                acc[i][j] = __builtin_amdgcn_mfma_f32_16x16x32_bf16(ah[i], bh[j], acc[i][j], 0, 0, 0);

        __syncthreads();
        cur ^= 1;
    }

    float b4[4];
    #pragma unroll
    for (int f = 0; f < 4; ++f) b4[f] = bias[n0 + wc + f * 16 + l15];
    #pragma unroll
    for (int i = 0; i < 2; ++i)
        #pragma unroll
        for (int j = 0; j < 4; ++j) {
            const int m = m0 + wr + i * 16 + l4 * 4 + j;
            const size_t row = (size_t)m * GN + n0 + wc;
            #pragma unroll
            for (int f = 0; f < 4; ++f)
                OutF[row + f * 16 + l15] = acc[i][f][j] + b4[f];
        }
}

// ---------------------------------------------------------------------------
// Causal flash attention, 1-term bf16, KVBLK=128 rounds, exact defer-rescale,
// XCD-aware swizzle (R30) + HW v_cvt_pk_bf16_f32 P-pack/epilogue (T12 prim):
// 1 inst converts+packs a float pair (RNE, same rounding as manual f2bf) —
// replaces ~28 bit-ops per ks-step with 4.
// ---------------------------------------------------------------------------
__global__ __launch_bounds__(256, 2)
void attn_mfma(const short* __restrict__ Qh, const short* __restrict__ Kh,
               const short* __restrict__ Vh, short* __restrict__ Oh)
{
    __shared__ short KhS[2][64][64];
    __shared__ short VhS[2][64][64];

    const int t    = threadIdx.x;
    const int lane = t & 63, wv = t >> 6;            // 4 waves
    const int l31  = lane & 31, hb = lane >> 5;

    // XCD-aware (bh, qt) derivation — bijective over 512 blocks
    const int lin = (int)blockIdx.y * 16 + (int)blockIdx.x;
    const int xcd = lin & 7;
    const int m   = lin >> 3;
    const int bh  = xcd * 4 + (m >> 4);
    const int qtr = m & 15;
    const int qt  = ((m >> 5) & 1) ? qtr : 15 - qtr;

    const int bb   = bh >> 4, hh = bh & 15;
    const int q0   = qt * 128;
    const int wq0  = wv * 32;

    const size_t kpan = (size_t)bh * SEQ * HDIM;   // [t][d] panels (Q,K)
    const size_t vpan = (size_t)bh * HDIM * SEQ;   // [d][t] panels (V^T)

    const int sr0  = t >> 3, sr1 = 32 + (t >> 3);
    const int scg  = t & 7;
    const int soff = scg * 8;
    const int lc0  = (scg ^ (sr0 & 7)) * 8;        // (sr1&7)==(sr0&7)

    // Q B-frags: col q = q0+wq0+l31, k-dim d = ds*16 + hb*8 + j
    bf16x8 qfh[4];
    {
        const size_t qrow = kpan + (size_t)(q0 + wq0 + l31) * HDIM;
        #pragma unroll
        for (int ds = 0; ds < 4; ++ds)
            qfh[ds] = *(const bf16x8*)&Qh[qrow + ds * 16 + hb * 8];
    }

    f32x16 oacc0 = (f32x16)(0.0f), oacc1 = (f32x16)(0.0f);
    float m_run = -1e30f, l_run = 0.f;

    const int NR = qt + 1;                 // rounds of 128 k

    int4v pK[2][2], pV[2][2];              // [k-half][row-half]
    #pragma unroll
    for (int h = 0; h < 2; ++h) {
        const int kb0 = h * 64;
        pK[h][0] = *(const int4v*)&Kh[kpan + (size_t)(kb0 + sr0) * HDIM + soff];
        pK[h][1] = *(const int4v*)&Kh[kpan + (size_t)(kb0 + sr1) * HDIM + soff];
        pV[h][0] = *(const int4v*)&Vh[vpan + (size_t)sr0 * SEQ + kb0 + soff];
        pV[h][1] = *(const int4v*)&Vh[vpan + (size_t)sr1 * SEQ + kb0 + soff];
    }

    for (int rr = 0; rr < NR; ++rr) {
        const int k0 = rr * 128;

        __syncthreads();           // all waves done reading prev K/V

        #pragma unroll
        for (int h = 0; h < 2; ++h) {
            *(int4v*)&KhS[h][sr0][lc0] = pK[h][0];
            *(int4v*)&KhS[h][sr1][lc0] = pK[h][1];
            *(int4v*)&VhS[h][sr0][lc0] = pV[h][0];
            *(int4v*)&VhS[h][sr1][lc0] = pV[h][1];
        }

        if (rr + 1 < NR) {         // T14: issue next round's loads under compute
            const int kn = k0 + 128;
            #pragma unroll
            for (int h = 0; h < 2; ++h) {
                const int kb0 = kn + h * 64;
                pK[h][0] = *(const int4v*)&Kh[kpan + (size_t)(kb0 + sr0) * HDIM + soff];
                pK[h][1] = *(const int4v*)&Kh[kpan + (size_t)(kb0 + sr1) * HDIM + soff];
                pV[h][0] = *(const int4v*)&Vh[vpan + (size_t)sr0 * SEQ + kb0 + soff];
                pV[h][1] = *(const int4v*)&Vh[vpan + (size_t)sr1 * SEQ + kb0 + soff];
            }
        }
        __syncthreads();           // current round's LDS ready

        #pragma unroll
        for (int half = 0; half < 2; ++half) {
            const int kk0 = k0 + half * 64;
            if (kk0 > q0 + wq0 + 31) continue;   // sub-tile future for wave

            // ---- QK^T 1-term: s0 (k rows 0-31), s1 (k rows 32-63) ----
            f32x16 s0 = (f32x16)(0.0f), s1 = (f32x16)(0.0f);
            #pragma unroll
            for (int ds = 0; ds < 4; ++ds) {
                const int g = ((ds * 2 + hb) ^ (l31 & 7)) * 8;
                const bf16x8 kh0 = *(const bf16x8*)&KhS[half][l31][g];
                const bf16x8 kh1 = *(const bf16x8*)&KhS[half][32 + l31][g];
                s0 = MFMA32(kh0, qfh[ds], s0);
                s1 = MFMA32(kh1, qfh[ds], s1);
            }

            // ---- causal mask (diag kept) ----
            if (kk0 + 63 > q0 + wq0) {
                const int qg = q0 + wq0 + l31;
                #pragma unroll
                for (int reg = 0; reg < 16; ++reg) {
                    const int kk = kk0 + (reg & 3) + 8 * (reg >> 2) + 4 * hb;
                    if (kk > qg)      s0[reg] = -1e30f;
                    if (kk + 32 > qg) s1[reg] = -1e30f;
                }
            }

            // ---- online softmax; exact skip of rescale when max static ----
            {
                float mx = -1e30f;
                #pragma unroll
                for (int reg = 0; reg < 16; ++reg)
                    mx = fmaxf(mx, fmaxf(s0[reg], s1[reg]));
                mx = fmaxf(mx, __shfl_xor(mx, 32));
                if (__any(mx > m_run)) {
                    const float mnew = fmaxf(m_run, mx);
                    const float scf  = fexp2(m_run - mnew);
                    m_run = mnew;
                    l_run *= scf;
                    #pragma unroll
                    for (int reg = 0; reg < 16; ++reg) {
                        oacc0[reg] *= scf;
                        oacc1[reg] *= scf;
                    }
                }
                float ls = 0.f;
                #pragma unroll
                for (int reg = 0; reg < 16; ++reg) {
                    const float p0 = fexp2(s0[reg] - m_run);
                    const float p1 = fexp2(s1[reg] - m_run);
                    s0[reg] = p0; s1[reg] = p1;
                    ls += p0 + p1;
                }
                ls += __shfl_xor(ls, 32);
                l_run += ls;
            }

            // ---- PV: per 16-k step, P packed via HW cvt_pk (1 inst/pair) ----
            #pragma unroll
            for (int ks = 0; ks < 4; ++ks) {
                const int sb = (ks & 1) * 8;
                unsigned hA0, hA1, hB0, hB1;
                if (ks >= 2) {
                    hA0 = cvtpk(s1[sb + 0], s1[sb + 1]);
                    hA1 = cvtpk(s1[sb + 2], s1[sb + 3]);
                    hB0 = cvtpk(s1[sb + 4], s1[sb + 5]);
                    hB1 = cvtpk(s1[sb + 6], s1[sb + 7]);
                } else {
                    hA0 = cvtpk(s0[sb + 0], s0[sb + 1]);
                    hA1 = cvtpk(s0[sb + 2], s0[sb + 3]);
                    hB0 = cvtpk(s0[sb + 4], s0[sb + 5]);
                    hB1 = cvtpk(s0[sb + 6], s0[sb + 7]);
                }
                const unsigned hr0 = (unsigned)__shfl_xor((int)(hb ? hA0 : hB0), 32);
                const unsigned hr1 = (unsigned)__shfl_xor((int)(hb ? hA1 : hB1), 32);
                const int4v wih = (int4v){(int)(hb ? hr0 : hA0), (int)(hb ? hr1 : hA1),
                                          (int)(hb ? hB0 : hr0), (int)(hb ? hB1 : hr1)};
                const bf16x8 pfh = __builtin_bit_cast(bf16x8, wih);

                const int gv = ((ks * 2 + hb) ^ (l31 & 7)) * 8;
                const bf16x8 vh0 = *(const bf16x8*)&VhS[half][l31][gv];
                const bf16x8 vh1 = *(const bf16x8*)&VhS[half][32 + l31][gv];
                oacc0 = MFMA32(vh0, pfh, oacc0);
                oacc1 = MFMA32(vh1, pfh, oacc1);
            }
        }
    }

    // epilogue: normalize, HW cvt_pk pack, write O hi-only (uint2 stores)
    const float inv = 1.f / l_run;
    const int q = q0 + wq0 + l31;
    const size_t row = ((size_t)(bb * SEQ + q)) * EMB + hh * HDIM;
    #pragma unroll
    for (int db = 0; db < 2; ++db)
        #pragma unroll
        for (int b = 0; b < 4; ++b) {
            const float v0 = (db ? oacc1[4 * b + 0] : oacc0[4 * b + 0]) * inv;
            const float v1 = (db ? oacc1[4 * b + 1] : oacc0[4 * b + 1]) * inv;
            const float v2 = (db ? oacc1[4 * b + 2] : oacc0[4 * b + 2]) * inv;
            const float v3 = (db ? oacc1[4 * b + 3] : oacc0[4 * b + 3]) * inv;
            uint2 w2;
            w2.x = cvtpk(v0, v1);
            w2.y = cvtpk(v2, v3);
            const int d0 = db * 32 + 8 * b + 4 * hb;
            *(uint2*)&Oh[row + d0] = w2;
        }
}

// ---------------------------------------------------------------------------
extern "C" void kernel_launch(void* const* d_in, const int* in_sizes, int n_in,
                              void* d_out, int out_size, void* d_ws, size_t ws_size,
                              hipStream_t stream)
{
    const float* x  = (const float*)d_in[0];
    const float* Wk = (const float*)d_in[1];
    const float* Wq = (const float*)d_in[2];
    const float* Wv = (const float*)d_in[3];
    const float* Wu = (const float*)d_in[4];
    const float* bu = (const float*)d_in[5];
    const float* kg = (const float*)d_in[6];
    const float* kb = (const float*)d_in[7];
    const float* qg = (const float*)d_in[8];
    const float* qb = (const float*)d_in[9];
    float* out = (float*)d_out;

    // ws map (32 MB):
    //  [ 0, 8M) Xh -> reused as Oh (attn out)
    //  [ 8,16M) Kh
    //  [16,24M) Qh
    //  [24,32M) W4h (4x2MB)
    // d_out: [0,8M) VTh (dead before final GEMM writes) -> final fp32 out
    char* w = (char*)d_ws;
    short* XhP = (short*)(w);
    short* KhP = (short*)(w + (8u  << 20));
    short* QhP = (short*)(w + (16u << 20));
    short* W4h = (short*)(w + (24u << 20));
    short* VTh = (short*)d_out;

    const float inv4 = 0.17677669529663687f;   // 1024^(-1/4)
    const float l2e  = 1.4426950408889634f;

    cvt_all<<<dim3(4096, 5), 256, 0, stream>>>(x, XhP, Wk, Wq, Wv, Wu, W4h);

    gemm_kqv<<<dim3(GN / 128, MROWS / 128, 3), 256, 0, stream>>>(
        XhP, W4h, kg, kb, qg, qb, inv4, inv4 * l2e,
        KhP, QhP, VTh);

    attn_mfma<<<dim3(SEQ / 128, BATCH * NHEADS), 256, 0, stream>>>(
        QhP, KhP, VTh, XhP);

    gemm_out<<<dim3(GN / 128, MROWS / 64), 256, 0, stream>>>(
        XhP, W4h + (3u << 20), bu, out);
}

// Round 32
// 109.200 us; speedup vs baseline: 1.0781x; 1.0380x over previous
//
#include <hip/hip_runtime.h>
#include <math.h>

#define EMB 1024
#define NHEADS 16
#define HDIM 64
#define BATCH 2
#define SEQ 2048
#define MROWS (BATCH*SEQ)   /* 4096 */
#define LN_EPS 1e-5f
#define GK 1024
#define GN 1024

typedef __attribute__((ext_vector_type(8))) short bf16x8;
typedef __attribute__((ext_vector_type(4))) short s16x4;
typedef __attribute__((ext_vector_type(4))) float f32x4;
typedef __attribute__((ext_vector_type(16))) float f32x16;
typedef __attribute__((ext_vector_type(4))) int int4v;

__device__ __forceinline__ short f2bf(float f) {     // RNE float->bf16
    union { float f; unsigned u; } v; v.f = f;
    unsigned r = v.u + 0x7FFFu + ((v.u >> 16) & 1u);
    return (short)(r >> 16);
}
__device__ __forceinline__ float bf2f(short s) {
    union { unsigned u; float f; } v; v.u = ((unsigned)(unsigned short)s) << 16;
    return v.f;
}
// HW packed f32->bf16 (RNE): dst = {lo: bf16(a), hi: bf16(b)} in 1 VALU inst
__device__ __forceinline__ unsigned cvtpk(float a, float b) {
    unsigned r;
    asm("v_cvt_pk_bf16_f32 %0, %1, %2" : "=v"(r) : "v"(a), "v"(b));
    return r;
}
// raw v_exp_f32: 2^x in one instruction (exp2f libm call costs +13us — R17)
__device__ __forceinline__ float fexp2(float x) {
    return __builtin_amdgcn_exp2f(x);
}

__device__ __forceinline__ void gload16(const short* g, short* l) {
    __builtin_amdgcn_global_load_lds(
        (const __attribute__((address_space(1))) unsigned*)g,
        (__attribute__((address_space(3))) unsigned*)l, 16, 0, 0);
}

#define MFMA32(a, b, c) __builtin_amdgcn_mfma_f32_32x32x16_bf16(a, b, c, 0, 0, 0)

// Bank-conflict-free GEMM LDS (verified R20: conflicts 6.29M -> 0):
// physical 16B granule c of row r holds logical granule (c-(r>>1))&3.
#define SRC_G(r, c)  ((((c) - ((r) >> 1)) & 3) * 8)
#define RD_G(r, l4)  ((((l4) + ((r) >> 1)) & 3) * 8)

// ---------------------------------------------------------------------------
// Fused converter: blockIdx.y==0 -> x fp32 -> bf16 hi; y in 1..4 -> weight
// z-1 -> bf16 hi only.
// ---------------------------------------------------------------------------
__global__ __launch_bounds__(256)
void cvt_all(const float* __restrict__ X, short* __restrict__ XH,
             const float* __restrict__ W0, const float* __restrict__ W1,
             const float* __restrict__ W2, const float* __restrict__ W3,
             short* __restrict__ WH)
{
    const int zy = blockIdx.y;
    if (zy == 0) {
        const size_t i = (size_t)blockIdx.x * 1024 + threadIdx.x * 4;
        const float4 v = *(const float4*)&X[i];
        s16x4 h;
        h[0] = f2bf(v.x); h[1] = f2bf(v.y);
        h[2] = f2bf(v.z); h[3] = f2bf(v.w);
        *(s16x4*)&XH[i] = h;
    } else {
        const int z = zy - 1;
        if (blockIdx.x >= 1024) return;        // weights are 1M floats each
        const float* W = (z == 0) ? W0 : (z == 1) ? W1 : (z == 2) ? W2 : W3;
        const size_t i = (size_t)blockIdx.x * 1024 + threadIdx.x * 4;
        const float4 v = *(const float4*)&W[i];
        s16x4 h;
        h[0] = f2bf(v.x); h[1] = f2bf(v.y);
        h[2] = f2bf(v.z); h[3] = f2bf(v.w);
        *(s16x4*)&WH[((size_t)z << 20) + i] = h;
    }
}

// ---------------------------------------------------------------------------
// Fused K/Q/V MFMA GEMM, pure bf16, 3-buffer counted-vmcnt pipeline (R27).
// z=0: K hi + LN. z=1: Q hi + LN. z=2: V^T hi.
// ---------------------------------------------------------------------------
__global__ __launch_bounds__(256, 3)
void gemm_kqv(const short* __restrict__ Xh, const short* __restrict__ W4h,
              const float* __restrict__ kg, const float* __restrict__ kb,
              const float* __restrict__ qg, const float* __restrict__ qb,
              float scaleK, float scaleQ,
              short* __restrict__ KhP, short* __restrict__ QhP,
              short* __restrict__ VTh)
{
    __shared__ short AhS[3][128][32], BhS[3][128][32];

    const int t   = threadIdx.x;
    const int ln  = t & 63, wv = t >> 6;
    const int l15 = ln & 15, l4 = ln >> 4;
    const int m0  = blockIdx.y * 128;
    const int n0  = blockIdx.x * 128;
    const int z   = blockIdx.z;
    const int wr  = (wv >> 1) * 64, wc = (wv & 1) * 64;

    const short* Bh = W4h + ((size_t)z << 20);

    const short* gplane = (wv < 2) ? Xh : Bh;
    const int    grow0  = (wv < 2) ? m0 : n0;
    short* lbase = (wv < 2) ? &AhS[0][0][0] : &BhS[0][0][0];
    const int s0 = (wv & 1) ? 4 : 0;           // 4 segs per wave, balanced

    f32x4 acc[4][4];
    #pragma unroll
    for (int i = 0; i < 4; ++i)
        #pragma unroll
        for (int j = 0; j < 4; ++j) acc[i][j] = (f32x4){0.f, 0.f, 0.f, 0.f};

    // prologue: stage k-steps 0 and 1 into bufs 0,1 (8 loads in flight)
    #pragma unroll
    for (int s = 0; s < 4; ++s) {
        const int chunk = (s0 + s) * 64 + ln;
        const int r = chunk >> 2, c = chunk & 3;
        gload16(gplane + (size_t)(grow0 + r) * GK + SRC_G(r, c),
                lbase + (s0 + s) * 512);
    }
    #pragma unroll
    for (int s = 0; s < 4; ++s) {
        const int chunk = (s0 + s) * 64 + ln;
        const int r = chunk >> 2, c = chunk & 3;
        gload16(gplane + (size_t)(grow0 + r) * GK + 32 + SRC_G(r, c),
                lbase + 4096 + (s0 + s) * 512);
    }
    asm volatile("s_waitcnt vmcnt(4)" ::: "memory");   // buf0 landed
    __builtin_amdgcn_s_barrier();

    int cur = 0;
    for (int i = 0; i < 32; ++i) {
        const int cur2 = (cur == 0) ? 2 : cur - 1;     // (i+2)%3
        if (i + 2 < 32) {          // stage k-step i+2 into freed buffer
            short* lp = lbase + cur2 * 4096;
            const int kof = (i + 2) * 32;
            #pragma unroll
            for (int s = 0; s < 4; ++s) {
                const int chunk = (s0 + s) * 64 + ln;
                const int r = chunk >> 2, c = chunk & 3;
                gload16(gplane + (size_t)(grow0 + r) * GK + kof + SRC_G(r, c),
                        lp + (s0 + s) * 512);
            }
        }

        bf16x8 ah[4], bh[4];
        #pragma unroll
        for (int f = 0; f < 4; ++f) {
            const int ra = wr + f * 16 + l15;
            const int rb = wc + f * 16 + l15;
            ah[f] = *(const bf16x8*)&AhS[cur][ra][RD_G(ra, l4)];
            bh[f] = *(const bf16x8*)&BhS[cur][rb][RD_G(rb, l4)];
        }
        #pragma unroll
        for (int i2 = 0; i2 < 4; ++i2)
            #pragma unroll
            for (int j = 0; j < 4; ++j)
                acc[i2][j] = __builtin_amdgcn_mfma_f32_16x16x32_bf16(ah[i2], bh[j], acc[i2][j], 0, 0, 0);

        if (i + 2 < 32) {
            asm volatile("s_waitcnt vmcnt(4)" ::: "memory");  // buf i+1 landed
        } else if (i + 1 < 32) {
            asm volatile("s_waitcnt vmcnt(0)" ::: "memory");  // tail: drain
        }
        __builtin_amdgcn_s_barrier();
        cur = (cur == 2) ? 0 : cur + 1;
    }

    if (z < 2) {
        const float* gamma = (z == 0) ? kg : qg;
        const float* beta  = (z == 0) ? kb : qb;
        short* OutH = (z == 0) ? KhP : QhP;
        const float scl = (z == 0) ? scaleK : scaleQ;
        const int n_head = (n0 + wc) >> 6;
        float g4[4], b4[4];
        #pragma unroll
        for (int f = 0; f < 4; ++f) {
            g4[f] = gamma[f * 16 + l15];
            b4[f] = beta [f * 16 + l15];
        }
        #pragma unroll
        for (int i = 0; i < 4; ++i)
            #pragma unroll
            for (int j = 0; j < 4; ++j) {
                const float v0 = acc[i][0][j], v1 = acc[i][1][j];
                const float v2 = acc[i][2][j], v3 = acc[i][3][j];
                float s1 = v0 + v1 + v2 + v3;
                float s2 = v0*v0 + v1*v1 + v2*v2 + v3*v3;
                s1 += __shfl_xor(s1, 1); s2 += __shfl_xor(s2, 1);
                s1 += __shfl_xor(s1, 2); s2 += __shfl_xor(s2, 2);
                s1 += __shfl_xor(s1, 4); s2 += __shfl_xor(s2, 4);
                s1 += __shfl_xor(s1, 8); s2 += __shfl_xor(s2, 8);
                const float mu  = s1 * (1.f / 64.f);
                const float var = s2 * (1.f / 64.f) - mu * mu;
                const float rs  = rsqrtf(var + LN_EPS);
                const int m = m0 + wr + i * 16 + l4 * 4 + j;   // m = b*SEQ + t
                const size_t orow =
                    ((size_t)((m >> 11) * NHEADS + n_head) * SEQ + (m & (SEQ - 1))) * HDIM;
                #pragma unroll
                for (int f = 0; f < 4; ++f) {
                    const float y = ((acc[i][f][j] - mu) * rs * g4[f] + b4[f]) * scl;
                    OutH[orow + f * 16 + l15] = f2bf(y);
                }
            }
    } else {
        // V^T epilogue: hi plane only (attn reads V as plain bf16)
        #pragma unroll
        for (int i = 0; i < 4; ++i)
            #pragma unroll
            for (int f = 0; f < 4; ++f) {
                s16x4 h4;
                #pragma unroll
                for (int j = 0; j < 4; ++j) h4[j] = f2bf(acc[i][f][j]);
                const int n  = n0 + wc + f * 16 + l15;
                const int hh = n >> 6, dd = n & 63;
                const int mb = m0 + wr + i * 16 + l4 * 4;      // j=0 row
                const size_t oa =
                    (((size_t)((mb >> 11) * NHEADS + hh)) * HDIM + dd) * SEQ + (mb & (SEQ - 1));
                *(s16x4*)&VTh[oa] = h4;
            }
    }
}

// ---------------------------------------------------------------------------
// Final GEMM, pure bf16, 2-phase dbuf (R26 measured config, unchanged).
// ---------------------------------------------------------------------------
__global__ __launch_bounds__(256, 2)
void gemm_out(const short* __restrict__ Ah, const short* __restrict__ Bh,
              const float* __restrict__ bias, float* __restrict__ OutF)
{
    __shared__ short AhS[2][64][32], BhS[2][128][32];

    const int t   = threadIdx.x;
    const int ln  = t & 63, wv = t >> 6;
    const int l15 = ln & 15, l4 = ln >> 4;
    const int m0  = blockIdx.y * 64;
    const int n0  = blockIdx.x * 128;
    const int wr  = (wv >> 1) * 32, wc = (wv & 1) * 64;

    const short* gplane = (wv == 0) ? Ah : Bh;
    const int    grow0  = (wv == 0) ? m0 : n0;
    const int    s0     = (wv == 2) ? 4 : 0;
    const int    nseg   = (wv < 3) ? 4 : 0;
    const int    bstep  = (wv == 0) ? 2048 : 4096;      // shorts per buffer
    short* lbase = (wv == 0) ? &AhS[0][0][0] : &BhS[0][0][0];

    f32x4 acc[2][4];
    #pragma unroll
    for (int i = 0; i < 2; ++i)
        #pragma unroll
        for (int j = 0; j < 4; ++j) acc[i][j] = (f32x4){0.f, 0.f, 0.f, 0.f};

    for (int s = 0; s < nseg; ++s) {
        const int chunk = (s0 + s) * 64 + ln;
        const int r = chunk >> 2, c = chunk & 3;
        gload16(gplane + (size_t)(grow0 + r) * GK + SRC_G(r, c),
                lbase + (s0 + s) * 512);
    }
    __syncthreads();

    int cur = 0;
    for (int k0 = 0; k0 < GK; k0 += 32) {
        if (k0 + 32 < GK) {
            short* lp = lbase + (cur ^ 1) * bstep;
            for (int s = 0; s < nseg; ++s) {
                const int chunk = (s0 + s) * 64 + ln;
                const int r = chunk >> 2, c = chunk & 3;
                gload16(gplane + (size_t)(grow0 + r) * GK + k0 + 32 + SRC_G(r, c),
                        lp + (s0 + s) * 512);
            }
        }

        bf16x8 ah[2], bh[4];
        #pragma unroll
        for (int f = 0; f < 2; ++f) {
            const int ra = wr + f * 16 + l15;
            ah[f] = *(const bf16x8*)&AhS[cur][ra][RD_G(ra, l4)];
        }
        #pragma unroll
        for (int f = 0; f < 4; ++f) {
            const int rb = wc + f * 16 + l15;
            bh[f] = *(const bf16x8*)&BhS[cur][rb][RD_G(rb, l4)];
        }
        #pragma unroll
        for (int i = 0; i < 2; ++i)
            #pragma unroll
            for (int j = 0; j < 4; ++j)
                acc[i][j] = __builtin_amdgcn_mfma_f32_16x16x32_bf16(ah[i], bh[j], acc[i][j], 0, 0, 0);

        __syncthreads();
        cur ^= 1;
    }

    float b4[4];
    #pragma unroll
    for (int f = 0; f < 4; ++f) b4[f] = bias[n0 + wc + f * 16 + l15];
    #pragma unroll
    for (int i = 0; i < 2; ++i)
        #pragma unroll
        for (int j = 0; j < 4; ++j) {
            const int m = m0 + wr + i * 16 + l4 * 4 + j;
            const size_t row = (size_t)m * GN + n0 + wc;
            #pragma unroll
            for (int f = 0; f < 4; ++f)
                OutF[row + f * 16 + l15] = acc[i][f][j] + b4[f];
        }
}

// ---------------------------------------------------------------------------
// Causal flash attention, 1-term bf16, WITHIN-BLOCK K-SPLIT: 8 waves/block,
// wave = (q-stripe 0..3, k-half 0..1). Same 512 blocks, same LDS, ZERO extra
// traffic (unlike R16/R23/R24 splits) — waves/CU double to 16 and the serial
// chain per wave halves. Private (m,l,O) per wave; end-of-kernel two-way
// flash combine via retired K/V LDS (kh=1 posts bf16-packed partial O + m,l).
// KVBLK=128 rounds, exact defer-rescale, XCD swizzle, HW cvt_pk (R29-R31).
// ---------------------------------------------------------------------------
__global__ __launch_bounds__(512, 4)
void attn_mfma(const short* __restrict__ Qh, const short* __restrict__ Kh,
               const short* __restrict__ Vh, short* __restrict__ Oh)
{
    __shared__ short KhS[2][64][64];
    __shared__ short VhS[2][64][64];

    const int t    = threadIdx.x;
    const int lane = t & 63, wv = t >> 6;            // 8 waves
    const int l31  = lane & 31, hb = lane >> 5;
    const int stripe = wv & 3, kh2 = wv >> 2;        // q-stripe, k-half

    // XCD-aware (bh, qt) derivation — bijective over 512 blocks (R30)
    const int lin = (int)blockIdx.y * 16 + (int)blockIdx.x;
    const int xcd = lin & 7;
    const int m   = lin >> 3;
    const int bh  = xcd * 4 + (m >> 4);
    const int qtr = m & 15;
    const int qt  = ((m >> 5) & 1) ? qtr : 15 - qtr;

    const int bb   = bh >> 4, hh = bh & 15;
    const int q0   = qt * 128;
    const int wq0  = stripe * 32;

    const size_t kpan = (size_t)bh * SEQ * HDIM;   // [t][d] panels (Q,K)
    const size_t vpan = (size_t)bh * HDIM * SEQ;   // [d][t] panels (V^T)

    // staging: 512 threads, 4 x 16B chunks each (2 K + 2 V of half u8)
    const int u    = t & 255, u8 = t >> 8;
    const int sr0  = u >> 3, sr1 = 32 + (u >> 3);
    const int scg  = u & 7;
    const int soff = scg * 8;
    const int lc0  = (scg ^ (sr0 & 7)) * 8;        // (sr1&7)==(sr0&7)

    // Q B-frags: col q = q0+wq0+l31, k-dim d = ds*16 + hb*8 + j
    bf16x8 qfh[4];
    {
        const size_t qrow = kpan + (size_t)(q0 + wq0 + l31) * HDIM;
        #pragma unroll
        for (int ds = 0; ds < 4; ++ds)
            qfh[ds] = *(const bf16x8*)&Qh[qrow + ds * 16 + hb * 8];
    }

    f32x16 oacc0 = (f32x16)(0.0f), oacc1 = (f32x16)(0.0f);
    float m_run = -1e30f, l_run = 0.f;

    const int NR = qt + 1;                 // rounds of 128 k

    int4v pK0, pK1, pV0, pV1;
    {
        const int kb0 = u8 * 64;
        pK0 = *(const int4v*)&Kh[kpan + (size_t)(kb0 + sr0) * HDIM + soff];
        pK1 = *(const int4v*)&Kh[kpan + (size_t)(kb0 + sr1) * HDIM + soff];
        pV0 = *(const int4v*)&Vh[vpan + (size_t)sr0 * SEQ + kb0 + soff];
        pV1 = *(const int4v*)&Vh[vpan + (size_t)sr1 * SEQ + kb0 + soff];
    }

    for (int rr = 0; rr < NR; ++rr) {
        const int k0 = rr * 128;

        __syncthreads();           // all waves done reading prev K/V

        *(int4v*)&KhS[u8][sr0][lc0] = pK0;
        *(int4v*)&KhS[u8][sr1][lc0] = pK1;
        *(int4v*)&VhS[u8][sr0][lc0] = pV0;
        *(int4v*)&VhS[u8][sr1][lc0] = pV1;

        if (rr + 1 < NR) {         // T14: issue next round's loads under compute
            const int kb0 = k0 + 128 + u8 * 64;
            pK0 = *(const int4v*)&Kh[kpan + (size_t)(kb0 + sr0) * HDIM + soff];
            pK1 = *(const int4v*)&Kh[kpan + (size_t)(kb0 + sr1) * HDIM + soff];
            pV0 = *(const int4v*)&Vh[vpan + (size_t)sr0 * SEQ + kb0 + soff];
            pV1 = *(const int4v*)&Vh[vpan + (size_t)sr1 * SEQ + kb0 + soff];
        }
        __syncthreads();           // current round's LDS ready

        #pragma unroll
        for (int half = 0; half < 2; ++half) {
            const int kw0 = k0 + half * 64 + kh2 * 32;   // wave's 32-k range
            if (kw0 > q0 + wq0 + 31) continue;           // entirely future

            // ---- QK^T 1-term on this wave's 32 k rows ----
            f32x16 s = (f32x16)(0.0f);
            #pragma unroll
            for (int ds = 0; ds < 4; ++ds) {
                const int g = ((ds * 2 + hb) ^ (l31 & 7)) * 8;
                const bf16x8 kf = *(const bf16x8*)&KhS[half][kh2 * 32 + l31][g];
                s = MFMA32(kf, qfh[ds], s);
            }

            // ---- causal mask (diag kept) ----
            if (kw0 + 31 > q0 + wq0) {
                const int qg = q0 + wq0 + l31;
                #pragma unroll
                for (int reg = 0; reg < 16; ++reg) {
                    const int kk = kw0 + (reg & 3) + 8 * (reg >> 2) + 4 * hb;
                    if (kk > qg) s[reg] = -1e30f;
                }
            }

            // ---- online softmax; exact skip of rescale when max static ----
            {
                float mx = -1e30f;
                #pragma unroll
                for (int reg = 0; reg < 16; ++reg) mx = fmaxf(mx, s[reg]);
                mx = fmaxf(mx, __shfl_xor(mx, 32));
                if (__any(mx > m_run)) {
                    const float mnew = fmaxf(m_run, mx);
                    const float scf  = fexp2(m_run - mnew);
                    m_run = mnew;
                    l_run *= scf;
                    #pragma unroll
                    for (int reg = 0; reg < 16; ++reg) {
                        oacc0[reg] *= scf;
                        oacc1[reg] *= scf;
                    }
                }
                float ls = 0.f;
                #pragma unroll
                for (int reg = 0; reg < 16; ++reg) {
                    const float p = fexp2(s[reg] - m_run);
                    s[reg] = p;
                    ls += p;
                }
                ls += __shfl_xor(ls, 32);
                l_run += ls;
            }

            // ---- PV: 2 ks-steps over this wave's k rows, HW cvt_pk pack ----
            #pragma unroll
            for (int ks2 = 0; ks2 < 2; ++ks2) {
                const int ks = kh2 * 2 + ks2;
                const int sb = ks2 * 8;
                const unsigned hA0 = cvtpk(s[sb + 0], s[sb + 1]);
                const unsigned hA1 = cvtpk(s[sb + 2], s[sb + 3]);
                const unsigned hB0 = cvtpk(s[sb + 4], s[sb + 5]);
                const unsigned hB1 = cvtpk(s[sb + 6], s[sb + 7]);
                const unsigned hr0 = (unsigned)__shfl_xor((int)(hb ? hA0 : hB0), 32);
                const unsigned hr1 = (unsigned)__shfl_xor((int)(hb ? hA1 : hB1), 32);
                const int4v wih = (int4v){(int)(hb ? hr0 : hA0), (int)(hb ? hr1 : hA1),
                                          (int)(hb ? hB0 : hr0), (int)(hb ? hB1 : hr1)};
                const bf16x8 pfh = __builtin_bit_cast(bf16x8, wih);

                const int gv = ((ks * 2 + hb) ^ (l31 & 7)) * 8;
                const bf16x8 vh0 = *(const bf16x8*)&VhS[half][l31][gv];
                const bf16x8 vh1 = *(const bf16x8*)&VhS[half][32 + l31][gv];
                oacc0 = MFMA32(vh0, pfh, oacc0);
                oacc1 = MFMA32(vh1, pfh, oacc1);
            }
        }
    }

    // ---- cross-wave combine: kh=1 posts partials through retired LDS ----
    __syncthreads();               // everyone done with K/V tiles
    unsigned* oscr = (unsigned*)&KhS[0][0][0];   // 4*64*16 u32 = 16KB (exact)
    float*    mls  = (float*)&VhS[0][0][0];      // 4*64*2 floats = 2KB

    if (kh2 == 1) {
        const int base = (stripe * 64 + lane) * 16;
        #pragma unroll
        for (int i = 0; i < 8; ++i)
            oscr[base + i]     = cvtpk(oacc0[2 * i], oacc0[2 * i + 1]);
        #pragma unroll
        for (int i = 0; i < 8; ++i)
            oscr[base + 8 + i] = cvtpk(oacc1[2 * i], oacc1[2 * i + 1]);
        mls[(stripe * 64 + lane) * 2]     = m_run;
        mls[(stripe * 64 + lane) * 2 + 1] = l_run;
    }
    __syncthreads();

    if (kh2 == 0) {
        const float mB = mls[(stripe * 64 + lane) * 2];
        const float lB = mls[(stripe * 64 + lane) * 2 + 1];
        const float mm = fmaxf(m_run, mB);
        const float fa = fexp2(m_run - mm);
        const float fb = fexp2(mB - mm);
        const float inv = 1.f / (l_run * fa + lB * fb);
        const int base = (stripe * 64 + lane) * 16;

        const int q = q0 + wq0 + l31;
        const size_t row = ((size_t)(bb * SEQ + q)) * EMB + hh * HDIM;
        #pragma unroll
        for (int db = 0; db < 2; ++db)
            #pragma unroll
            for (int b = 0; b < 4; ++b) {
                const int pi = db * 8 + 2 * b;           // u32 pair index
                const unsigned uB0 = oscr[base + pi];
                const unsigned uB1 = oscr[base + pi + 1];
                const float a0 = (db ? oacc1[4 * b + 0] : oacc0[4 * b + 0]);
                const float a1 = (db ? oacc1[4 * b + 1] : oacc0[4 * b + 1]);
                const float a2 = (db ? oacc1[4 * b + 2] : oacc0[4 * b + 2]);
                const float a3 = (db ? oacc1[4 * b + 3] : oacc0[4 * b + 3]);
                const float v0 = (a0 * fa + bf2f((short)(uB0 & 0xffff))  * fb) * inv;
                const float v1 = (a1 * fa + bf2f((short)(uB0 >> 16))    * fb) * inv;
                const float v2 = (a2 * fa + bf2f((short)(uB1 & 0xffff)) * fb) * inv;
                const float v3 = (a3 * fa + bf2f((short)(uB1 >> 16))    * fb) * inv;
                uint2 w2;
                w2.x = cvtpk(v0, v1);
                w2.y = cvtpk(v2, v3);
                const int d0 = db * 32 + 8 * b + 4 * hb;
                *(uint2*)&Oh[row + d0] = w2;
            }
    }
}

// ---------------------------------------------------------------------------
extern "C" void kernel_launch(void* const* d_in, const int* in_sizes, int n_in,
                              void* d_out, int out_size, void* d_ws, size_t ws_size,
                              hipStream_t stream)
{
    const float* x  = (const float*)d_in[0];
    const float* Wk = (const float*)d_in[1];
    const float* Wq = (const float*)d_in[2];
    const float* Wv = (const float*)d_in[3];
    const float* Wu = (const float*)d_in[4];
    const float* bu = (const float*)d_in[5];
    const float* kg = (const float*)d_in[6];
    const float* kb = (const float*)d_in[7];
    const float* qg = (const float*)d_in[8];
    const float* qb = (const float*)d_in[9];
    float* out = (float*)d_out;

    // ws map (32 MB):
    //  [ 0, 8M) Xh -> reused as Oh (attn out)
    //  [ 8,16M) Kh
    //  [16,24M) Qh
    //  [24,32M) W4h (4x2MB)
    // d_out: [0,8M) VTh (dead before final GEMM writes) -> final fp32 out
    char* w = (char*)d_ws;
    short* XhP = (short*)(w);
    short* KhP = (short*)(w + (8u  << 20));
    short* QhP = (short*)(w + (16u << 20));
    short* W4h = (short*)(w + (24u << 20));
    short* VTh = (short*)d_out;

    const float inv4 = 0.17677669529663687f;   // 1024^(-1/4)
    const float l2e  = 1.4426950408889634f;

    cvt_all<<<dim3(4096, 5), 256, 0, stream>>>(x, XhP, Wk, Wq, Wv, Wu, W4h);

    gemm_kqv<<<dim3(GN / 128, MROWS / 128, 3), 256, 0, stream>>>(
        XhP, W4h, kg, kb, qg, qb, inv4, inv4 * l2e,
        KhP, QhP, VTh);

    attn_mfma<<<dim3(SEQ / 128, BATCH * NHEADS), 512, 0, stream>>>(
        QhP, KhP, VTh, XhP);

    gemm_out<<<dim3(GN / 128, MROWS / 64), 256, 0, stream>>>(
        XhP, W4h + (3u << 20), bu, out);
}